// Round 10
// baseline (156.670 us; speedup 1.0000x reference)
//
#include <hip/hip_runtime.h>
#include <math.h>

#define WIN 11
#define IMG_H 384
#define IMG_W 512
#define OUT_H (IMG_H - WIN + 1)   // 374
#define OUT_W (IMG_W - WIN + 1)   // 502
#define NIMG 48
#define NBLOCKS (OUT_H * NIMG)    // 17952 one-wave blocks, 1 output row each
#define BPX (NBLOCKS / 8)         // 2244 blocks per XCD
#define NBUCKETS 256

struct GaussW { float g[WIN]; };

// One wave = one output row. 40 accumulator floats (5 ch x 8 cols) — the
// whole kernel's live set fits the allocator's natural ~64-VGPR squeeze, so
// nothing overflows into AGPRs (r6-r9 lesson: attributes can't stop the
// squeeze; only a small live set avoids the v_accvgpr shuttle that cost
// ~14 us of VALU-busy at RPW=2's 80-float acc).
__global__ void ssim_fused_kernel(
    const float* __restrict__ X, const float* __restrict__ Y,
    double* __restrict__ accum, GaussW gw)
{
    const int lane = threadIdx.x & 63;

    // XCD-aware swizzle: dispatch is round-robin id%8 across XCDs; give each
    // XCD a CONTIGUOUS run of (img, row) work so the 10-row halo overlap
    // between adjacent rows hits that XCD's private 4 MB L2.
    const int id  = blockIdx.x;
    const int wid = (id & 7) * BPX + (id >> 3);
    const int img = wid / OUT_H;
    const int r0  = wid % OUT_H;          // max input row = 373+10 = 383: no clamp
    const int c0  = lane << 3;            // this lane's 8 columns
    const float* __restrict__ Xb = X + ((size_t)img * IMG_H + r0) * IMG_W + c0;
    const float* __restrict__ Yb = Y + ((size_t)img * IMG_H + r0) * IMG_W + c0;

    // ---- vertical 11-tap, 1 output row, streaming 11 input rows ----
    float a0[8], a1[8], a2[8], a3[8], a4[8];   // m1, m2, xx, yy, xy
    #pragma unroll
    for (int j = 0; j < 8; ++j) { a0[j] = a1[j] = a2[j] = a3[j] = a4[j] = 0.f; }

    #pragma unroll
    for (int k = 0; k < WIN; ++k) {
        const float* rx = Xb + (size_t)k * IMG_W;
        const float* ry = Yb + (size_t)k * IMG_W;
        float4 xa = *(const float4*)(rx);
        float4 xb = *(const float4*)(rx + 4);
        float4 ya = *(const float4*)(ry);
        float4 yb = *(const float4*)(ry + 4);
        float xs[8] = {xa.x, xa.y, xa.z, xa.w, xb.x, xb.y, xb.z, xb.w};
        float ys[8] = {ya.x, ya.y, ya.z, ya.w, yb.x, yb.y, yb.z, yb.w};
        const float g = gw.g[k];
        #pragma unroll
        for (int j = 0; j < 8; ++j) {
            float x = xs[j], y = ys[j];
            a0[j] = fmaf(g, x, a0[j]);
            a1[j] = fmaf(g, y, a1[j]);
            float t = g * x;
            a2[j] = fmaf(t, x, a2[j]);
            a4[j] = fmaf(t, y, a4[j]);
            float u = g * y;
            a3[j] = fmaf(u, y, a3[j]);
        }
    }

    // ---- horizontal 11-tap per channel (acc dies as h is born) ----
    // halo via wave shuffles; lane-63 wraps feed only masked-out columns.
    float h[5][8];
    #pragma unroll
    for (int ch = 0; ch < 5; ++ch) {
        float* acc = (ch == 0) ? a0 : (ch == 1) ? a1 : (ch == 2) ? a2
                   : (ch == 3) ? a3 : a4;
        float v[18];
        #pragma unroll
        for (int j = 0; j < 8; ++j) v[j] = acc[j];
        #pragma unroll
        for (int j = 0; j < 8; ++j) v[8 + j] = __shfl(acc[j], lane + 1, 64);
        v[16] = __shfl(acc[0], lane + 2, 64);
        v[17] = __shfl(acc[1], lane + 2, 64);
        #pragma unroll
        for (int j = 0; j < 8; ++j) {
            float o = 0.f;
            #pragma unroll
            for (int k = 0; k < WIN; ++k) o = fmaf(gw.g[k], v[j + k], o);
            h[ch][j] = o;
        }
    }

    // ---- SSIM epilogue ----
    const float C1 = 1e-4f, C2 = 9e-4f;
    float sum = 0.f;
    #pragma unroll
    for (int j = 0; j < 8; ++j) {
        float mu1 = h[0][j], mu2 = h[1][j];
        float mu1s = mu1 * mu1, mu2s = mu2 * mu2, m12 = mu1 * mu2;
        float s1  = h[2][j] - mu1s;
        float s2  = h[3][j] - mu2s;
        float s12 = h[4][j] - m12;
        float num = fmaf(2.f, m12, C1) * fmaf(2.f, s12, C2);
        float den = (mu1s + mu2s + C1) * (s1 + s2 + C2);
        float ssim = num * __builtin_amdgcn_rcpf(den);
        sum += (c0 + j < OUT_W) ? ssim : 0.f;
    }

    // ---- wave reduction -> one f64 atomic per wave, bucketed ----
    #pragma unroll
    for (int off = 32; off; off >>= 1)
        sum += __shfl_down(sum, off, 64);
    if (lane == 0)
        atomicAdd(&accum[id & (NBUCKETS - 1)], (double)sum);
}

__global__ void ssim_finalize_kernel(const double* __restrict__ accum,
                                     float* __restrict__ out, double inv_count)
{
    const int lane = threadIdx.x;
    double s = 0.0;
    for (int i = lane; i < NBUCKETS; i += 64) s += accum[i];
    #pragma unroll
    for (int off = 32; off; off >>= 1)
        s += __shfl_down(s, off, 64);
    if (lane == 0) out[0] = (float)(1.0 - s * inv_count);
}

extern "C" void kernel_launch(void* const* d_in, const int* in_sizes, int n_in,
                              void* d_out, int out_size, void* d_ws, size_t ws_size,
                              hipStream_t stream) {
    const float* X = (const float*)d_in[0];
    const float* Y = (const float*)d_in[1];
    float* out = (float*)d_out;
    double* accum = (double*)d_ws;

    GaussW gw;
    {
        double g[WIN], ssum = 0.0;
        for (int i = 0; i < WIN; ++i) {
            double d = (double)i - WIN / 2;
            g[i] = exp(-(d * d) / (2.0 * 1.5 * 1.5));
            ssum += g[i];
        }
        for (int i = 0; i < WIN; ++i) gw.g[i] = (float)(g[i] / ssum);
    }

    // d_ws is re-poisoned 0xAA before every call — zero the buckets.
    hipMemsetAsync(accum, 0, NBUCKETS * sizeof(double), stream);

    ssim_fused_kernel<<<NBLOCKS, 64, 0, stream>>>(X, Y, accum, gw);

    const double inv_count = 1.0 / ((double)NIMG * OUT_H * OUT_W);
    ssim_finalize_kernel<<<1, 64, 0, stream>>>(accum, out, inv_count);
}

// Round 11
// 129.426 us; speedup vs baseline: 1.2105x; 1.2105x over previous
//
#include <hip/hip_runtime.h>
#include <math.h>

#define WIN 11
#define IMG_H 384
#define IMG_W 512
#define OUT_H (IMG_H - WIN + 1)   // 374
#define OUT_W (IMG_W - WIN + 1)   // 502
#define RPW 2                     // output rows per wave
#define NPAIRS (OUT_H / RPW)      // 187 (exact: 374 = 2*187)
#define NIMG 48
#define NBLOCKS (NPAIRS * NIMG)   // 8976 one-wave blocks
#define BPX (NBLOCKS / 8)         // 1122 blocks per XCD
#define NBUCKETS 256

typedef float v2 __attribute__((ext_vector_type(2)));

struct GaussW { float g[WIN]; };

__device__ __forceinline__ v2 shfl_v2(v2 v, int src) {
    v2 r; r.x = __shfl(v.x, src, 64); r.y = __shfl(v.y, src, 64); return r;
}

// Horizontal 11-tap on a packed-channel array (v2 lanes = 2 SSIM channels,
// array index = column). Halo via wave shuffles.
__device__ __forceinline__ void horiz11_v2(const v2 (&A)[8], v2 (&out)[8],
                                           int lane, const GaussW& gw)
{
    v2 V[18];
    #pragma unroll
    for (int j = 0; j < 8; ++j) V[j] = A[j];
    #pragma unroll
    for (int j = 0; j < 8; ++j) V[8 + j] = shfl_v2(A[j], lane + 1);
    V[16] = shfl_v2(A[0], lane + 2);
    V[17] = shfl_v2(A[1], lane + 2);
    #pragma unroll
    for (int j = 0; j < 8; ++j) {
        v2 o = 0.f;
        #pragma unroll
        for (int k = 0; k < WIN; ++k) {
            v2 g = gw.g[k];
            o = __builtin_elementwise_fma(g, V[j + k], o);  // v_pk_fma_f32
        }
        out[j] = o;
    }
}

__device__ __forceinline__ void horiz11_f(const float (&A)[8], float (&out)[8],
                                          int lane, const GaussW& gw)
{
    float V[18];
    #pragma unroll
    for (int j = 0; j < 8; ++j) V[j] = A[j];
    #pragma unroll
    for (int j = 0; j < 8; ++j) V[8 + j] = __shfl(A[j], lane + 1, 64);
    V[16] = __shfl(A[0], lane + 2, 64);
    V[17] = __shfl(A[1], lane + 2, 64);
    #pragma unroll
    for (int j = 0; j < 8; ++j) {
        float o = 0.f;
        #pragma unroll
        for (int k = 0; k < WIN; ++k) o = fmaf(gw.g[k], V[j + k], o);
        out[j] = o;
    }
}

// TENSOR-PACKED math: v2 p = {x, y} fuses {m1,m2} and {xx,yy} channel pairs
// into single v_pk_fma_f32 ops (4 instrs per col-row-k vs 7 scalar), with no
// extra pair-building temps (r7's column-packing mistake). Live set stays 80
// floats = r9's. Register attributes proven useless (r8/r9/r10: allocator
// always minimizes arch VGPRs, overflow shuttles via AGPRs) — so the win is
// fewer real instructions AND fewer shuttled accumulator touches (3 vs 5).
__global__
__attribute__((amdgpu_flat_work_group_size(64, 64), amdgpu_waves_per_eu(3, 4)))
void ssim_fused_kernel(
    const float* __restrict__ X, const float* __restrict__ Y,
    double* __restrict__ accum, GaussW gw)
{
    const int lane = threadIdx.x & 63;

    // XCD-aware swizzle: round-robin id%8 across XCDs -> contiguous
    // (img, row-pair) runs per XCD so halo rows hit its private 4 MB L2.
    const int id   = blockIdx.x;
    const int wid  = (id & 7) * BPX + (id >> 3);
    const int img  = wid / NPAIRS;
    const int pair = wid % NPAIRS;
    const int r0   = pair * RPW;          // max input row = 372+11 = 383: no clamp
    const int c0   = lane << 3;           // this lane's 8 columns
    const float* __restrict__ Xb = X + ((size_t)img * IMG_H + r0) * IMG_W + c0;
    const float* __restrict__ Yb = Y + ((size_t)img * IMG_H + r0) * IMG_W + c0;

    // Accumulators: a01 = {m1,m2}, a23 = {xx,yy}, a4 = xy
    v2 a01[RPW][8], a23[RPW][8];
    float a4[RPW][8];
    #pragma unroll
    for (int r = 0; r < RPW; ++r)
        #pragma unroll
        for (int j = 0; j < 8; ++j) { a01[r][j] = 0.f; a23[r][j] = 0.f; a4[r][j] = 0.f; }

    #pragma unroll
    for (int k = 0; k < RPW + WIN - 1; ++k) {   // 12 input rows
        const float* rx = Xb + (size_t)k * IMG_W;
        const float* ry = Yb + (size_t)k * IMG_W;
        float4 xa = *(const float4*)(rx);
        float4 xb = *(const float4*)(rx + 4);
        float4 ya = *(const float4*)(ry);
        float4 yb = *(const float4*)(ry + 4);
        v2 p[8] = {{xa.x, ya.x}, {xa.y, ya.y}, {xa.z, ya.z}, {xa.w, ya.w},
                   {xb.x, yb.x}, {xb.y, yb.y}, {xb.z, yb.z}, {xb.w, yb.w}};
        #pragma unroll
        for (int r = 0; r < RPW; ++r) {
            if (k - r >= 0 && k - r < WIN) {     // compile-time after unroll
                v2 g = gw.g[k - r];
                #pragma unroll
                for (int j = 0; j < 8; ++j) {
                    v2 q = p[j];
                    a01[r][j] = __builtin_elementwise_fma(g, q, a01[r][j]);
                    v2 t = g * q;                                  // {gx, gy}
                    a23[r][j] = __builtin_elementwise_fma(t, q, a23[r][j]);
                    a4[r][j]  = fmaf(t.x, q.y, a4[r][j]);          // g*x*y
                }
            }
        }
    }

    // ---- horizontal + epilogue per row ----
    const float C1 = 1e-4f, C2 = 9e-4f;
    float sum = 0.f;
    #pragma unroll
    for (int r = 0; r < RPW; ++r) {
        v2 h01[8], h23[8];
        float h4[8];
        horiz11_v2(a01[r], h01, lane, gw);
        horiz11_v2(a23[r], h23, lane, gw);
        horiz11_f (a4[r],  h4,  lane, gw);
        #pragma unroll
        for (int j = 0; j < 8; ++j) {
            v2 mu = h01[j];
            v2 sq = mu * mu;                    // {mu1², mu2²}
            float m12 = mu.x * mu.y;
            v2 sig = h23[j] - sq;               // {s1, s2}
            float s12 = h4[j] - m12;
            float num = fmaf(2.f, m12, C1) * fmaf(2.f, s12, C2);
            float den = (sq.x + sq.y + C1) * (sig.x + sig.y + C2);
            float ssim = num * __builtin_amdgcn_rcpf(den);
            sum += (c0 + j < OUT_W) ? ssim : 0.f;
        }
    }

    // ---- wave reduction -> one f64 atomic per wave, bucketed ----
    #pragma unroll
    for (int off = 32; off; off >>= 1)
        sum += __shfl_down(sum, off, 64);
    if (lane == 0)
        atomicAdd(&accum[id & (NBUCKETS - 1)], (double)sum);
}

__global__ void ssim_finalize_kernel(const double* __restrict__ accum,
                                     float* __restrict__ out, double inv_count)
{
    const int lane = threadIdx.x;
    double s = 0.0;
    for (int i = lane; i < NBUCKETS; i += 64) s += accum[i];
    #pragma unroll
    for (int off = 32; off; off >>= 1)
        s += __shfl_down(s, off, 64);
    if (lane == 0) out[0] = (float)(1.0 - s * inv_count);
}

extern "C" void kernel_launch(void* const* d_in, const int* in_sizes, int n_in,
                              void* d_out, int out_size, void* d_ws, size_t ws_size,
                              hipStream_t stream) {
    const float* X = (const float*)d_in[0];
    const float* Y = (const float*)d_in[1];
    float* out = (float*)d_out;
    double* accum = (double*)d_ws;

    GaussW gw;
    {
        double g[WIN], ssum = 0.0;
        for (int i = 0; i < WIN; ++i) {
            double d = (double)i - WIN / 2;
            g[i] = exp(-(d * d) / (2.0 * 1.5 * 1.5));
            ssum += g[i];
        }
        for (int i = 0; i < WIN; ++i) gw.g[i] = (float)(g[i] / ssum);
    }

    // d_ws is re-poisoned 0xAA before every call — zero the buckets.
    hipMemsetAsync(accum, 0, NBUCKETS * sizeof(double), stream);

    ssim_fused_kernel<<<NBLOCKS, 64, 0, stream>>>(X, Y, accum, gw);

    const double inv_count = 1.0 / ((double)NIMG * OUT_H * OUT_W);
    ssim_finalize_kernel<<<1, 64, 0, stream>>>(accum, out, inv_count);
}

// Round 12
// 125.403 us; speedup vs baseline: 1.2493x; 1.0321x over previous
//
#include <hip/hip_runtime.h>
#include <math.h>

#define WIN 11
#define IMG_H 384
#define IMG_W 512
#define OUT_H (IMG_H - WIN + 1)   // 374
#define OUT_W (IMG_W - WIN + 1)   // 502
#define RPW 2                     // output rows per wave
#define NPAIRS 187                // per image (exact: 374 = 2*187)
#define NIMG 48
#define TOTAL_PAIRS (NPAIRS * NIMG)   // 8976
#define WPB 4                     // independent waves per block (no barriers)
#define NBLOCKS 2248              // ceil(8976/4) padded to 8*281 for swizzle
#define BPX 281                   // blocks per XCD
#define NBUCKETS 256

typedef float v2 __attribute__((ext_vector_type(2)));

struct GaussW { float g[WIN]; };

__device__ __forceinline__ v2 shfl_v2(v2 v, int src) {
    v2 r; r.x = __shfl(v.x, src, 64); r.y = __shfl(v.y, src, 64); return r;
}

__device__ __forceinline__ void horiz11_v2(const v2 (&A)[8], v2 (&out)[8],
                                           int lane, const GaussW& gw)
{
    v2 V[18];
    #pragma unroll
    for (int j = 0; j < 8; ++j) V[j] = A[j];
    #pragma unroll
    for (int j = 0; j < 8; ++j) V[8 + j] = shfl_v2(A[j], lane + 1);
    V[16] = shfl_v2(A[0], lane + 2);
    V[17] = shfl_v2(A[1], lane + 2);
    #pragma unroll
    for (int j = 0; j < 8; ++j) {
        v2 o = 0.f;
        #pragma unroll
        for (int k = 0; k < WIN; ++k) {
            v2 g = gw.g[k];
            o = __builtin_elementwise_fma(g, V[j + k], o);  // v_pk_fma_f32
        }
        out[j] = o;
    }
}

__device__ __forceinline__ void horiz11_f(const float (&A)[8], float (&out)[8],
                                          int lane, const GaussW& gw)
{
    float V[18];
    #pragma unroll
    for (int j = 0; j < 8; ++j) V[j] = A[j];
    #pragma unroll
    for (int j = 0; j < 8; ++j) V[8 + j] = __shfl(A[j], lane + 1, 64);
    V[16] = __shfl(A[0], lane + 2, 64);
    V[17] = __shfl(A[1], lane + 2, 64);
    #pragma unroll
    for (int j = 0; j < 8; ++j) {
        float o = 0.f;
        #pragma unroll
        for (int k = 0; k < WIN; ++k) o = fmaf(gw.g[k], V[j + k], o);
        out[j] = o;
    }
}

// r12 change vs r11: ONLY the launch structure. 256-thread blocks of 4
// independent waves (no barriers/LDS) escape the ~8 workgroup-slots/CU limit
// that capped 1-wave blocks at ~8 waves/CU (r6/r8/r9/r11 all plateaued
// there). At VGPR~72, 4-wave WGs x ~7 slots -> ~28 waves/CU: the 11 us/wave
// memory-stall (48 serialized float4 loads) gets covered by TLP instead of
// unobtainable register-level ILP (r8-r10: allocator always minimizes VGPRs).
__global__ __launch_bounds__(256) void ssim_fused_kernel(
    const float* __restrict__ X, const float* __restrict__ Y,
    double* __restrict__ accum, GaussW gw)
{
    const int wave = threadIdx.x >> 6;
    const int lane = threadIdx.x & 63;

    // Block-level XCD swizzle (id%8 -> XCD round-robin, contiguous run per
    // XCD); waves within a block take adjacent row-pairs (shared halo in L1).
    const int id = blockIdx.x;
    const int wb = (id & 7) * BPX + (id >> 3);
    const int P  = wb * WPB + wave;        // global row-pair index
    if (P >= TOTAL_PAIRS) return;          // 16 pad waves; no barriers -> safe

    const int img  = P / NPAIRS;
    const int pair = P % NPAIRS;
    const int r0   = pair * RPW;          // max input row = 372+11 = 383: no clamp
    const int c0   = lane << 3;           // this lane's 8 columns
    const float* __restrict__ Xb = X + ((size_t)img * IMG_H + r0) * IMG_W + c0;
    const float* __restrict__ Yb = Y + ((size_t)img * IMG_H + r0) * IMG_W + c0;

    // Accumulators: a01 = {m1,m2}, a23 = {xx,yy}, a4 = xy (tensor-packed)
    v2 a01[RPW][8], a23[RPW][8];
    float a4[RPW][8];
    #pragma unroll
    for (int r = 0; r < RPW; ++r)
        #pragma unroll
        for (int j = 0; j < 8; ++j) { a01[r][j] = 0.f; a23[r][j] = 0.f; a4[r][j] = 0.f; }

    #pragma unroll
    for (int k = 0; k < RPW + WIN - 1; ++k) {   // 12 input rows
        const float* rx = Xb + (size_t)k * IMG_W;
        const float* ry = Yb + (size_t)k * IMG_W;
        float4 xa = *(const float4*)(rx);
        float4 xb = *(const float4*)(rx + 4);
        float4 ya = *(const float4*)(ry);
        float4 yb = *(const float4*)(ry + 4);
        v2 p[8] = {{xa.x, ya.x}, {xa.y, ya.y}, {xa.z, ya.z}, {xa.w, ya.w},
                   {xb.x, yb.x}, {xb.y, yb.y}, {xb.z, yb.z}, {xb.w, yb.w}};
        #pragma unroll
        for (int r = 0; r < RPW; ++r) {
            if (k - r >= 0 && k - r < WIN) {     // compile-time after unroll
                v2 g = gw.g[k - r];
                #pragma unroll
                for (int j = 0; j < 8; ++j) {
                    v2 q = p[j];
                    a01[r][j] = __builtin_elementwise_fma(g, q, a01[r][j]);
                    v2 t = g * q;                                  // {gx, gy}
                    a23[r][j] = __builtin_elementwise_fma(t, q, a23[r][j]);
                    a4[r][j]  = fmaf(t.x, q.y, a4[r][j]);          // g*x*y
                }
            }
        }
    }

    // ---- horizontal + epilogue per row ----
    const float C1 = 1e-4f, C2 = 9e-4f;
    float sum = 0.f;
    #pragma unroll
    for (int r = 0; r < RPW; ++r) {
        v2 h01[8], h23[8];
        float h4[8];
        horiz11_v2(a01[r], h01, lane, gw);
        horiz11_v2(a23[r], h23, lane, gw);
        horiz11_f (a4[r],  h4,  lane, gw);
        #pragma unroll
        for (int j = 0; j < 8; ++j) {
            v2 mu = h01[j];
            v2 sq = mu * mu;                    // {mu1², mu2²}
            float m12 = mu.x * mu.y;
            v2 sig = h23[j] - sq;               // {s1, s2}
            float s12 = h4[j] - m12;
            float num = fmaf(2.f, m12, C1) * fmaf(2.f, s12, C2);
            float den = (sq.x + sq.y + C1) * (sig.x + sig.y + C2);
            float ssim = num * __builtin_amdgcn_rcpf(den);
            sum += (c0 + j < OUT_W) ? ssim : 0.f;
        }
    }

    // ---- wave reduction -> one f64 atomic per wave, bucketed ----
    #pragma unroll
    for (int off = 32; off; off >>= 1)
        sum += __shfl_down(sum, off, 64);
    if (lane == 0)
        atomicAdd(&accum[P & (NBUCKETS - 1)], (double)sum);
}

__global__ void ssim_finalize_kernel(const double* __restrict__ accum,
                                     float* __restrict__ out, double inv_count)
{
    const int lane = threadIdx.x;
    double s = 0.0;
    for (int i = lane; i < NBUCKETS; i += 64) s += accum[i];
    #pragma unroll
    for (int off = 32; off; off >>= 1)
        s += __shfl_down(s, off, 64);
    if (lane == 0) out[0] = (float)(1.0 - s * inv_count);
}

extern "C" void kernel_launch(void* const* d_in, const int* in_sizes, int n_in,
                              void* d_out, int out_size, void* d_ws, size_t ws_size,
                              hipStream_t stream) {
    const float* X = (const float*)d_in[0];
    const float* Y = (const float*)d_in[1];
    float* out = (float*)d_out;
    double* accum = (double*)d_ws;

    GaussW gw;
    {
        double g[WIN], ssum = 0.0;
        for (int i = 0; i < WIN; ++i) {
            double d = (double)i - WIN / 2;
            g[i] = exp(-(d * d) / (2.0 * 1.5 * 1.5));
            ssum += g[i];
        }
        for (int i = 0; i < WIN; ++i) gw.g[i] = (float)(g[i] / ssum);
    }

    // d_ws is re-poisoned 0xAA before every call — zero the buckets.
    hipMemsetAsync(accum, 0, NBUCKETS * sizeof(double), stream);

    ssim_fused_kernel<<<NBLOCKS, 64 * WPB, 0, stream>>>(X, Y, accum, gw);

    const double inv_count = 1.0 / ((double)NIMG * OUT_H * OUT_W);
    ssim_finalize_kernel<<<1, 64, 0, stream>>>(accum, out, inv_count);
}